// Round 13
// baseline (316.755 us; speedup 1.0000x reference)
//
#include <hip/hip_runtime.h>
#include <math.h>

#define N_PTS 16384
#define K_NBR 16
#define H_DIM 64
#define TS    512    // kNN LDS tile (points)
#define CAP   144    // per-row candidate buffer (entries)

typedef unsigned long long u64;
typedef float v2f __attribute__((ext_vector_type(2)));

// prefix count of set bits of m strictly below my lane
__device__ __forceinline__ int prefix_lt(u64 m) {
    return __builtin_amdgcn_mbcnt_hi((unsigned)(m >> 32),
           __builtin_amdgcn_mbcnt_lo((unsigned)m, 0));
}
// key = (order-preserving float bits, ~idx): sorts by value desc then idx asc
__device__ __forceinline__ u64 mkkey(unsigned vbits, unsigned idx) {
    unsigned of = vbits ^ (unsigned)(((int)vbits >> 31) | 0x80000000);
    return ((u64)of << 32) | (unsigned)(~idx);
}
__device__ __forceinline__ unsigned keyidx(u64 k) { return ~(unsigned)k; }

__device__ __forceinline__ float readlane_f(float v, int l) {
    return __uint_as_float(__builtin_amdgcn_readlane(__float_as_uint(v), l));
}

// 64-lane bitonic ascending sort, float
__device__ __forceinline__ float wave_sort_f32(float v, int lane) {
#pragma unroll
    for (int k = 2; k <= 64; k <<= 1) {
#pragma unroll
        for (int j = k >> 1; j > 0; j >>= 1) {
            float o = __shfl_xor(v, j, 64);
            bool keep_min = (((lane & k) == 0) == ((lane & j) == 0));
            v = keep_min ? fminf(v, o) : fmaxf(v, o);
        }
    }
    return v;
}
// 64-lane bitonic ascending sort, u64 keys
__device__ __forceinline__ u64 wave_sort_u64(u64 v, int lane) {
#pragma unroll
    for (int k = 2; k <= 64; k <<= 1) {
#pragma unroll
        for (int j = k >> 1; j > 0; j >>= 1) {
            u64 o = __shfl_xor((unsigned long long)v, j, 64);
            bool keep_min = (((lane & k) == 0) == ((lane & j) == 0));
            u64 mn = (v < o) ? v : o;
            u64 mx = (v < o) ? o : v;
            v = keep_min ? mn : mx;
        }
    }
    return v;
}

// raise tau to 16th-largest of per-lane max VALUES, drop entries below.
// Exact: tau <= 16th-largest value seen; >=-keep retains all boundary ties
// (which have lower indices than any future candidate).
__device__ __forceinline__ int wave_compact(uint2* buf, int cnt, float* tau,
                                            int lane) {
    float lm = -INFINITY;
    for (int s = lane; s < cnt; s += 64)
        lm = fmaxf(lm, __uint_as_float(buf[s].x));
    const float tv = readlane_f(wave_sort_f32(lm, lane), 48);
    int nc = 0;
    for (int s0 = 0; s0 < cnt; s0 += 64) {
        const int s = s0 + lane;
        uint2 e = make_uint2(0u, 0u);
        bool keep = false;
        if (s < cnt) { e = buf[s]; keep = (__uint_as_float(e.x) >= tv); }
        const u64 km = __ballot(keep);
        if (keep) buf[nc + prefix_lt(km)] = e;  // write idx <= read idx: safe
        nc += (int)__popcll(km);
    }
    *tau = tv;
    return nc;
}

// ---- planes: pl[c][i] = x[i].c for c<4; pl[4][i] = -xx[i] (squares->sum) --
__global__ __launch_bounds__(256) void plane_kernel(const float4* __restrict__ x4,
                                                    float* __restrict__ pl) {
    int i = blockIdx.x * 256 + threadIdx.x;
    float4 v = x4[i];
    float nxx;
    {
#pragma clang fp contract(off)
        float s0 = v.x * v.x;
        float s1 = v.y * v.y;
        float s2 = v.z * v.z;
        float s3 = v.w * v.w;
        nxx = -(((s0 + s1) + s2) + s3);
    }
    pl[0 * N_PTS + i] = v.x;
    pl[1 * N_PTS + i] = v.y;
    pl[2 * N_PTS + i] = v.z;
    pl[3 * N_PTS + i] = v.w;
    pl[4 * N_PTS + i] = nxx;
}

// ---------------- brute-force kNN: 2 rows/wave, pk-fp32 pairs, -------------
// double-buffered LDS staging with register-carried prefetch (12 VGPRs) ->
// one barrier per tile, global latency hidden by processing. Selection on
// p' = 2*xi.xj - xxj (row-constant shift of p: identical top-16 set/order).
__global__ __launch_bounds__(256, 8) void knn_kernel(
        const float4* __restrict__ x4,
        const float* __restrict__ pl,
        int* __restrict__ knn) {
    __shared__ __align__(16) float xsc[2][5][TS];  // 20 KB (dbuf, 5 planes)
    __shared__ uint2 buf[8][CAP];                  // 9 KB  (29 KB -> 5 blk/CU)
    const int lane = threadIdx.x & 63;
    const int wave = threadIdx.x >> 6;
    const int row0 = blockIdx.x * 8 + wave * 2;
    const int NT = N_PTS / TS;                     // 32 tiles

    float4 y[2]; uint2* bufr[2];
#pragma unroll
    for (int r = 0; r < 2; ++r) {
        const float4 t0 = x4[row0 + r];
        y[r] = make_float4(2.0f * t0.x, 2.0f * t0.y, 2.0f * t0.z, 2.0f * t0.w);
        bufr[r] = &buf[wave * 2 + r][0];
    }
    float tau[2]; int cnt[2];

    // staging: 5*TS/4 = 640 b128 chunks per tile, 2.5 per thread
    float4 st[3];
    auto issue = [&](int t) {                      // global -> regs, no wait
        const int base = t * TS;
#pragma unroll
        for (int j = 0; j < 3; ++j) {
            const int q = threadIdx.x + j * 256;
            if (q < 640) {
                const int c = q >> 7;              // plane 0..4
                const int i = (q & 127) << 2;
                st[j] = *(const float4*)&pl[c * N_PTS + base + i];
            }
        }
    };
    auto commit = [&](int b) {                     // regs -> LDS (waits vmcnt)
#pragma unroll
        for (int j = 0; j < 3; ++j) {
            const int q = threadIdx.x + j * 256;
            if (q < 640) {
                const int c = q >> 7;
                const int i = (q & 127) << 2;
                *(float4*)&xsc[b][c][i] = st[j];
            }
        }
    };

    // p' pair for candidates (e, e+1) in buffer b
    auto pair_p = [&](int b, int e, int r) -> v2f {
        const v2f ax = *(const v2f*)&xsc[b][0][e];
        const v2f ay = *(const v2f*)&xsc[b][1][e];
        const v2f az = *(const v2f*)&xsc[b][2][e];
        const v2f aw = *(const v2f*)&xsc[b][3][e];
        const v2f nx = *(const v2f*)&xsc[b][4][e];
        v2f acc = __builtin_elementwise_fma(ax, (v2f){y[r].x, y[r].x}, nx);
        acc = __builtin_elementwise_fma(ay, (v2f){y[r].y, y[r].y}, acc);
        acc = __builtin_elementwise_fma(az, (v2f){y[r].z, y[r].z}, acc);
        acc = __builtin_elementwise_fma(aw, (v2f){y[r].w, y[r].w}, acc);
        return acc;
    };

    auto do_iter = [&](int b, int cbase) {         // 128 candidates at cbase
        const int e = (cbase & (TS - 1)) + 2 * lane;
        v2f pp[2]; u64 mm[2];
#pragma unroll
        for (int r = 0; r < 2; ++r) {
            pp[r] = pair_p(b, e, r);
            mm[r] = __ballot(fmaxf(pp[r].x, pp[r].y) > tau[r]);
        }
        if (mm[0] | mm[1]) {                       // wave-uniform, rare
#pragma unroll
            for (int r = 0; r < 2; ++r) {
                if (mm[r]) {
                    u64 ma = __ballot(pp[r].x > tau[r]);
                    u64 mb = __ballot(pp[r].y > tau[r]);
                    int add = (int)__popcll(ma) + (int)__popcll(mb);
                    if (cnt[r] + add > CAP) {      // compact only when needed
                        cnt[r] = wave_compact(bufr[r], cnt[r], &tau[r], lane);
                        ma = __ballot(pp[r].x > tau[r]);
                        mb = __ballot(pp[r].y > tau[r]);
                        add = (int)__popcll(ma) + (int)__popcll(mb);
                    }
                    const int ca = (int)__popcll(ma);
                    if (pp[r].x > tau[r])
                        bufr[r][cnt[r] + prefix_lt(ma)] =
                            make_uint2(__float_as_uint(pp[r].x),
                                       (unsigned)(cbase + 2 * lane));
                    if (pp[r].y > tau[r])
                        bufr[r][cnt[r] + ca + prefix_lt(mb)] =
                            make_uint2(__float_as_uint(pp[r].y),
                                       (unsigned)(cbase + 2 * lane + 1));
                    cnt[r] += add;
                }
            }
        }
    };

    // ---- pipeline: tile 0 ----
    issue(0); commit(0);
    __syncthreads();
    issue(1);

    // seed from first 128 candidates (tau = 16th-largest of pair-maxima m16:
    // top-16 maxima are 16 distinct candidates >= m16 -> p16(128) >= m16 safe)
    {
        const int e = 2 * lane;
#pragma unroll
        for (int r = 0; r < 2; ++r) {
            const v2f pp = pair_p(0, e, r);
            const float mx = fmaxf(pp.x, pp.y);
            tau[r] = readlane_f(wave_sort_f32(mx, lane), 48);
            const u64 ma = __ballot(pp.x >= tau[r]);   // >= keeps ties
            const u64 mb = __ballot(pp.y >= tau[r]);
            const int ca = (int)__popcll(ma);
            if (pp.x >= tau[r])
                bufr[r][prefix_lt(ma)] =
                    make_uint2(__float_as_uint(pp.x), (unsigned)e);
            if (pp.y >= tau[r])
                bufr[r][ca + prefix_lt(mb)] =
                    make_uint2(__float_as_uint(pp.y), (unsigned)(e + 1));
            cnt[r] = ca + (int)__popcll(mb);
        }
    }
#pragma unroll
    for (int j = 1; j < TS / 128; ++j) do_iter(0, j * 128);

    // ---- pipeline: tiles 1..NT-1, one barrier per tile ----
    for (int t = 1; t < NT; ++t) {
        const int b = t & 1;
        commit(b);                 // waits vmcnt (covered by prior processing)
        __syncthreads();           // writes visible; prev readers done
        if (t + 1 < NT) issue(t + 1);
#pragma unroll
        for (int j = 0; j < TS / 128; ++j) do_iter(b, t * TS + j * 128);
    }

    // final: compact, one u64-key bitonic sort, lanes 48..63 = top-16
#pragma unroll
    for (int r = 0; r < 2; ++r) {
        const int c2 = wave_compact(bufr[r], cnt[r], &tau[r], lane);
        u64 key = 0;                               // sentinel < any real key
        if (lane < c2) {
            const uint2 e = bufr[r][lane];
            key = mkkey(e.x, e.y);
        }
        key = wave_sort_u64(key, lane);
        if (lane >= 48)
            knn[(row0 + r) * K_NBR + (lane - 48)] = (int)keyidx(key);
    }
}

// ---------------- edge-feature MLP (R12, proven): gather + hoisted W2 ------
__global__ __launch_bounds__(256, 2) void mlp_kernel(
        const float4* __restrict__ x4,
        const int* __restrict__ knn,
        const float4* __restrict__ W2f4,
        const float* __restrict__ W1,
        const float* __restrict__ b1,
        const float* __restrict__ b2,
        float* __restrict__ out) {
    __shared__ __align__(16) float4 w2s[16][64];     // 16 KB, h4-major
    __shared__ __align__(16) float  h1s[4][32][68];  // 34 KB, per-wave
    __shared__ __align__(16) float4 xjs[4][32];      // 2 KB, per-wave gather
    const int lane = threadIdx.x & 63;
    const int wave = threadIdx.x >> 6;
    const int kq   = lane >> 4;
    const int gp   = lane & 15;
    const int p0   = (blockIdx.x * 4 + wave) * 2;    // 2 points per wave

    for (int q = threadIdx.x; q < 1024; q += 256)
        w2s[q & 15][q >> 4] = W2f4[q];               // w2s[h4][g]
    __syncthreads();

    float w1r[8];
#pragma unroll
    for (int c = 0; c < 8; ++c) w1r[c] = W1[lane * 8 + c];
    const float b1r = b1[lane];
    float b2r[4];
#pragma unroll
    for (int gq = 0; gq < 4; ++gq) b2r[gq] = b2[gq * 16 + gp];

    // parallel gather: 32 indices coalesced, 32 x4 loads in flight at once
    if (lane < 32) {
        const int pp = lane >> 4;
        const int nb = knn[(p0 + pp) * K_NBR + (lane & 15)];
        xjs[wave][lane] = x4[nb];
    }
    // wave-private LDS + in-wave vmcnt/lgkmcnt ordering: no barrier

    // layer 1 for both points (lane = hidden feature h)
#pragma unroll
    for (int pp = 0; pp < 2; ++pp) {
        const float4 xi = x4[p0 + pp];
        float hb = b1r;
        hb = fmaf(w1r[4] - w1r[0], xi.x, hb);
        hb = fmaf(w1r[5] - w1r[1], xi.y, hb);
        hb = fmaf(w1r[6] - w1r[2], xi.z, hb);
        hb = fmaf(w1r[7] - w1r[3], xi.w, hb);
#pragma unroll
        for (int k = 0; k < K_NBR; ++k) {
            const float4 xj = xjs[wave][pp * 16 + k];
            float h = hb;
            h = fmaf(w1r[0], xj.x, h);
            h = fmaf(w1r[1], xj.y, h);
            h = fmaf(w1r[2], xj.z, h);
            h = fmaf(w1r[3], xj.w, h);
            h1s[wave][pp * 16 + k][lane] = fmaxf(h, 0.0f);
        }
    }

    // layer 2: acc[pp][kk][gq] (packed pairs over h), h4-outer, w4 hoisted
    v2f acc[2][4][4];
#pragma unroll
    for (int pp = 0; pp < 2; ++pp)
#pragma unroll
        for (int kk = 0; kk < 4; ++kk)
#pragma unroll
            for (int gq = 0; gq < 4; ++gq)
                acc[pp][kk][gq] = (v2f){b2r[gq], 0.0f};

#pragma unroll
    for (int h4 = 0; h4 < 16; ++h4) {
        float4 w4[4];
#pragma unroll
        for (int gq = 0; gq < 4; ++gq) w4[gq] = w2s[h4][gq * 16 + gp];
#pragma unroll
        for (int pp = 0; pp < 2; ++pp) {
#pragma unroll
            for (int kk = 0; kk < 4; ++kk) {
                const float4 hv =
                    *(const float4*)&h1s[wave][pp * 16 + kq * 4 + kk][h4 * 4];
#pragma unroll
                for (int gq = 0; gq < 4; ++gq) {
                    acc[pp][kk][gq] = __builtin_elementwise_fma(
                        (v2f){hv.x, hv.y}, (v2f){w4[gq].x, w4[gq].y},
                        acc[pp][kk][gq]);
                    acc[pp][kk][gq] = __builtin_elementwise_fma(
                        (v2f){hv.z, hv.w}, (v2f){w4[gq].z, w4[gq].w},
                        acc[pp][kk][gq]);
                }
            }
        }
    }

#pragma unroll
    for (int pp = 0; pp < 2; ++pp) {
        float s[4];
#pragma unroll
        for (int gq = 0; gq < 4; ++gq) {
            s[gq] = 0.0f;
#pragma unroll
            for (int kk = 0; kk < 4; ++kk) {
                const float v = acc[pp][kk][gq].x + acc[pp][kk][gq].y;
                s[gq] += fmaxf(v, 0.0f);
            }
        }
#pragma unroll
        for (int off = 16; off <= 32; off <<= 1)
#pragma unroll
            for (int gq = 0; gq < 4; ++gq)
                s[gq] += __shfl_xor(s[gq], off, 64);

        out[(p0 + pp) * H_DIM + kq * 16 + gp] = s[kq] * (1.0f / 16.0f);
    }
}

extern "C" void kernel_launch(void* const* d_in, const int* in_sizes, int n_in,
                              void* d_out, int out_size, void* d_ws, size_t ws_size,
                              hipStream_t stream) {
    (void)in_sizes; (void)n_in; (void)out_size; (void)ws_size;
    const float* x  = (const float*)d_in[0];
    const float* W1 = (const float*)d_in[1];
    const float* b1 = (const float*)d_in[2];
    const float* W2 = (const float*)d_in[3];
    const float* b2 = (const float*)d_in[4];
    float* out = (float*)d_out;

    float* pl  = (float*)d_ws;                                      // 5*N floats
    int*   knn = (int*)((char*)d_ws + 5 * N_PTS * sizeof(float));   // N*K ints

    const float4* x4 = (const float4*)x;

    plane_kernel<<<N_PTS / 256, 256, 0, stream>>>(x4, pl);
    knn_kernel  <<<N_PTS / 8,   256, 0, stream>>>(x4, pl, knn);
    mlp_kernel  <<<N_PTS / 8,   256, 0, stream>>>(
        x4, knn, (const float4*)W2, W1, b1, b2, out);
}

// Round 14
// 215.087 us; speedup vs baseline: 1.4727x; 1.4727x over previous
//
#include <hip/hip_runtime.h>
#include <math.h>

#define N_PTS 16384
#define K_NBR 16
#define H_DIM 64
#define TS    512    // kNN LDS tile (points)
#define CAP   144    // per-row candidate buffer (entries)

typedef unsigned long long u64;
typedef float v2f __attribute__((ext_vector_type(2)));

// prefix count of set bits of m strictly below my lane
__device__ __forceinline__ int prefix_lt(u64 m) {
    return __builtin_amdgcn_mbcnt_hi((unsigned)(m >> 32),
           __builtin_amdgcn_mbcnt_lo((unsigned)m, 0));
}
// key = (order-preserving float bits, ~idx): sorts by value desc then idx asc
__device__ __forceinline__ u64 mkkey(unsigned vbits, unsigned idx) {
    unsigned of = vbits ^ (unsigned)(((int)vbits >> 31) | 0x80000000);
    return ((u64)of << 32) | (unsigned)(~idx);
}
__device__ __forceinline__ unsigned keyidx(u64 k) { return ~(unsigned)k; }

__device__ __forceinline__ float readlane_f(float v, int l) {
    return __uint_as_float(__builtin_amdgcn_readlane(__float_as_uint(v), l));
}

// 64-lane bitonic ascending sort, float
__device__ __forceinline__ float wave_sort_f32(float v, int lane) {
#pragma unroll
    for (int k = 2; k <= 64; k <<= 1) {
#pragma unroll
        for (int j = k >> 1; j > 0; j >>= 1) {
            float o = __shfl_xor(v, j, 64);
            bool keep_min = (((lane & k) == 0) == ((lane & j) == 0));
            v = keep_min ? fminf(v, o) : fmaxf(v, o);
        }
    }
    return v;
}
// 64-lane bitonic ascending sort, u64 keys
__device__ __forceinline__ u64 wave_sort_u64(u64 v, int lane) {
#pragma unroll
    for (int k = 2; k <= 64; k <<= 1) {
#pragma unroll
        for (int j = k >> 1; j > 0; j >>= 1) {
            u64 o = __shfl_xor((unsigned long long)v, j, 64);
            bool keep_min = (((lane & k) == 0) == ((lane & j) == 0));
            u64 mn = (v < o) ? v : o;
            u64 mx = (v < o) ? o : v;
            v = keep_min ? mn : mx;
        }
    }
    return v;
}

// raise tau to 16th-largest of per-lane max VALUES, drop entries below.
// Exact: tau <= 16th-largest value seen; >=-keep retains all boundary ties
// (which have lower indices than any future candidate).
__device__ __forceinline__ int wave_compact(uint2* buf, int cnt, float* tau,
                                            int lane) {
    float lm = -INFINITY;
    for (int s = lane; s < cnt; s += 64)
        lm = fmaxf(lm, __uint_as_float(buf[s].x));
    const float tv = readlane_f(wave_sort_f32(lm, lane), 48);
    int nc = 0;
    for (int s0 = 0; s0 < cnt; s0 += 64) {
        const int s = s0 + lane;
        uint2 e = make_uint2(0u, 0u);
        bool keep = false;
        if (s < cnt) { e = buf[s]; keep = (__uint_as_float(e.x) >= tv); }
        const u64 km = __ballot(keep);
        if (keep) buf[nc + prefix_lt(km)] = e;  // write idx <= read idx: safe
        nc += (int)__popcll(km);
    }
    *tau = tv;
    return nc;
}

// ---- planes: pl[c][i] = x[i].c for c<4; pl[4][i] = -xx[i] (squares->sum) --
__global__ __launch_bounds__(256) void plane_kernel(const float4* __restrict__ x4,
                                                    float* __restrict__ pl) {
    int i = blockIdx.x * 256 + threadIdx.x;
    float4 v = x4[i];
    float nxx;
    {
#pragma clang fp contract(off)
        float s0 = v.x * v.x;
        float s1 = v.y * v.y;
        float s2 = v.z * v.z;
        float s3 = v.w * v.w;
        nxx = -(((s0 + s1) + s2) + s3);
    }
    pl[0 * N_PTS + i] = v.x;
    pl[1 * N_PTS + i] = v.y;
    pl[2 * N_PTS + i] = v.z;
    pl[3 * N_PTS + i] = v.w;
    pl[4 * N_PTS + i] = nxx;
}

// ---------------- brute-force kNN: 2 rows/wave, pk-fp32 candidate PAIRS ----
// R12 skeleton (synchronous stage, no register carry across processing —
// R10/R13 both spilled from exactly that) + plane staging: flat b128
// global->LDS copies, no per-tile transpose or scalar LDS writes.
// Selection on p' = 2*xi.xj - xxj (row-constant shift: identical top-16).
__global__ __launch_bounds__(256, 8) void knn_kernel(
        const float4* __restrict__ x4,
        const float* __restrict__ pl,
        int* __restrict__ knn) {
    __shared__ __align__(16) float xsc[5][TS];     // 10 KB, 5 planes
    __shared__ uint2 buf[8][CAP];                  // 9 KB  (19.25 KB -> 8/CU)
    const int lane = threadIdx.x & 63;
    const int wave = threadIdx.x >> 6;
    const int row0 = blockIdx.x * 8 + wave * 2;

    float4 y[2]; uint2* bufr[2];
#pragma unroll
    for (int r = 0; r < 2; ++r) {
        const float4 t0 = x4[row0 + r];
        y[r] = make_float4(2.0f * t0.x, 2.0f * t0.y, 2.0f * t0.z, 2.0f * t0.w);
        bufr[r] = &buf[wave * 2 + r][0];
    }
    float tau[2]; int cnt[2];

    // stage one tile: 640 b128 chunks, flat LDS layout == plane-major global
    auto stage = [&](int t) {
        const int base = t * TS;
        for (int q = threadIdx.x; q < 640; q += 256) {
            const float4 v = *(const float4*)
                &pl[(q >> 7) * N_PTS + base + ((q & 127) << 2)];
            *(float4*)((char*)&xsc[0][0] + ((size_t)q << 4)) = v;
        }
    };

    // p' pair for candidates (e, e+1)
    auto pair_p = [&](int e, int r) -> v2f {
        const v2f ax = *(const v2f*)&xsc[0][e];
        const v2f ay = *(const v2f*)&xsc[1][e];
        const v2f az = *(const v2f*)&xsc[2][e];
        const v2f aw = *(const v2f*)&xsc[3][e];
        const v2f nx = *(const v2f*)&xsc[4][e];
        v2f acc = __builtin_elementwise_fma(ax, (v2f){y[r].x, y[r].x}, nx);
        acc = __builtin_elementwise_fma(ay, (v2f){y[r].y, y[r].y}, acc);
        acc = __builtin_elementwise_fma(az, (v2f){y[r].z, y[r].z}, acc);
        acc = __builtin_elementwise_fma(aw, (v2f){y[r].w, y[r].w}, acc);
        return acc;
    };

    auto do_iter = [&](int cbase) {          // 128 candidates at cbase
        const int e = (cbase & (TS - 1)) + 2 * lane;
        v2f pp[2]; u64 mm[2];
#pragma unroll
        for (int r = 0; r < 2; ++r) {
            pp[r] = pair_p(e, r);
            mm[r] = __ballot(fmaxf(pp[r].x, pp[r].y) > tau[r]);
        }
        if (mm[0] | mm[1]) {                 // wave-uniform, rare post-seed
#pragma unroll
            for (int r = 0; r < 2; ++r) {
                if (mm[r]) {
                    u64 ma = __ballot(pp[r].x > tau[r]);
                    u64 mb = __ballot(pp[r].y > tau[r]);
                    int add = (int)__popcll(ma) + (int)__popcll(mb);
                    if (cnt[r] + add > CAP) {  // compact only when needed
                        cnt[r] = wave_compact(bufr[r], cnt[r], &tau[r], lane);
                        ma = __ballot(pp[r].x > tau[r]);
                        mb = __ballot(pp[r].y > tau[r]);
                        add = (int)__popcll(ma) + (int)__popcll(mb);
                    }
                    const int ca = (int)__popcll(ma);
                    if (pp[r].x > tau[r])
                        bufr[r][cnt[r] + prefix_lt(ma)] =
                            make_uint2(__float_as_uint(pp[r].x),
                                       (unsigned)(cbase + 2 * lane));
                    if (pp[r].y > tau[r])
                        bufr[r][cnt[r] + ca + prefix_lt(mb)] =
                            make_uint2(__float_as_uint(pp[r].y),
                                       (unsigned)(cbase + 2 * lane + 1));
                    cnt[r] += add;
                }
            }
        }
    };

    // ---- tile 0 ----
    stage(0);
    __syncthreads();

    // seed from first 128 candidates (tau = 16th-largest of pair-maxima m16:
    // top-16 maxima are 16 distinct candidates >= m16 -> p16(128) >= m16 safe)
    {
        const int e = 2 * lane;
#pragma unroll
        for (int r = 0; r < 2; ++r) {
            const v2f pp = pair_p(e, r);
            const float mx = fmaxf(pp.x, pp.y);
            tau[r] = readlane_f(wave_sort_f32(mx, lane), 48);
            const u64 ma = __ballot(pp.x >= tau[r]);   // >= keeps ties
            const u64 mb = __ballot(pp.y >= tau[r]);
            const int ca = (int)__popcll(ma);
            if (pp.x >= tau[r])
                bufr[r][prefix_lt(ma)] =
                    make_uint2(__float_as_uint(pp.x), (unsigned)e);
            if (pp.y >= tau[r])
                bufr[r][ca + prefix_lt(mb)] =
                    make_uint2(__float_as_uint(pp.y), (unsigned)(e + 1));
            cnt[r] = ca + (int)__popcll(mb);
        }
    }
#pragma unroll
    for (int j = 1; j < TS / 128; ++j) do_iter(j * 128);

    // ---- tiles 1..NT-1 ----
    for (int t = 1; t < N_PTS / TS; ++t) {
        __syncthreads();
        stage(t);
        __syncthreads();
#pragma unroll
        for (int j = 0; j < TS / 128; ++j) do_iter(t * TS + j * 128);
    }

    // final: compact, one u64-key bitonic sort, lanes 48..63 = top-16
#pragma unroll
    for (int r = 0; r < 2; ++r) {
        const int c2 = wave_compact(bufr[r], cnt[r], &tau[r], lane);
        u64 key = 0;                               // sentinel < any real key
        if (lane < c2) {
            const uint2 e = bufr[r][lane];
            key = mkkey(e.x, e.y);
        }
        key = wave_sort_u64(key, lane);
        if (lane >= 48)
            knn[(row0 + r) * K_NBR + (lane - 48)] = (int)keyidx(key);
    }
}

// ---------------- edge-feature MLP (R12, proven): gather + hoisted W2 ------
__global__ __launch_bounds__(256, 2) void mlp_kernel(
        const float4* __restrict__ x4,
        const int* __restrict__ knn,
        const float4* __restrict__ W2f4,
        const float* __restrict__ W1,
        const float* __restrict__ b1,
        const float* __restrict__ b2,
        float* __restrict__ out) {
    __shared__ __align__(16) float4 w2s[16][64];     // 16 KB, h4-major
    __shared__ __align__(16) float  h1s[4][32][68];  // 34 KB, per-wave
    __shared__ __align__(16) float4 xjs[4][32];      // 2 KB, per-wave gather
    const int lane = threadIdx.x & 63;
    const int wave = threadIdx.x >> 6;
    const int kq   = lane >> 4;
    const int gp   = lane & 15;
    const int p0   = (blockIdx.x * 4 + wave) * 2;    // 2 points per wave

    for (int q = threadIdx.x; q < 1024; q += 256)
        w2s[q & 15][q >> 4] = W2f4[q];               // w2s[h4][g]
    __syncthreads();

    float w1r[8];
#pragma unroll
    for (int c = 0; c < 8; ++c) w1r[c] = W1[lane * 8 + c];
    const float b1r = b1[lane];
    float b2r[4];
#pragma unroll
    for (int gq = 0; gq < 4; ++gq) b2r[gq] = b2[gq * 16 + gp];

    // parallel gather: 32 indices coalesced, 32 x4 loads in flight at once
    if (lane < 32) {
        const int pp = lane >> 4;
        const int nb = knn[(p0 + pp) * K_NBR + (lane & 15)];
        xjs[wave][lane] = x4[nb];
    }
    // wave-private LDS + in-wave vmcnt/lgkmcnt ordering: no barrier

    // layer 1 for both points (lane = hidden feature h)
#pragma unroll
    for (int pp = 0; pp < 2; ++pp) {
        const float4 xi = x4[p0 + pp];
        float hb = b1r;
        hb = fmaf(w1r[4] - w1r[0], xi.x, hb);
        hb = fmaf(w1r[5] - w1r[1], xi.y, hb);
        hb = fmaf(w1r[6] - w1r[2], xi.z, hb);
        hb = fmaf(w1r[7] - w1r[3], xi.w, hb);
#pragma unroll
        for (int k = 0; k < K_NBR; ++k) {
            const float4 xj = xjs[wave][pp * 16 + k];
            float h = hb;
            h = fmaf(w1r[0], xj.x, h);
            h = fmaf(w1r[1], xj.y, h);
            h = fmaf(w1r[2], xj.z, h);
            h = fmaf(w1r[3], xj.w, h);
            h1s[wave][pp * 16 + k][lane] = fmaxf(h, 0.0f);
        }
    }

    // layer 2: acc[pp][kk][gq] (packed pairs over h), h4-outer, w4 hoisted
    v2f acc[2][4][4];
#pragma unroll
    for (int pp = 0; pp < 2; ++pp)
#pragma unroll
        for (int kk = 0; kk < 4; ++kk)
#pragma unroll
            for (int gq = 0; gq < 4; ++gq)
                acc[pp][kk][gq] = (v2f){b2r[gq], 0.0f};

#pragma unroll
    for (int h4 = 0; h4 < 16; ++h4) {
        float4 w4[4];
#pragma unroll
        for (int gq = 0; gq < 4; ++gq) w4[gq] = w2s[h4][gq * 16 + gp];
#pragma unroll
        for (int pp = 0; pp < 2; ++pp) {
#pragma unroll
            for (int kk = 0; kk < 4; ++kk) {
                const float4 hv =
                    *(const float4*)&h1s[wave][pp * 16 + kq * 4 + kk][h4 * 4];
#pragma unroll
                for (int gq = 0; gq < 4; ++gq) {
                    acc[pp][kk][gq] = __builtin_elementwise_fma(
                        (v2f){hv.x, hv.y}, (v2f){w4[gq].x, w4[gq].y},
                        acc[pp][kk][gq]);
                    acc[pp][kk][gq] = __builtin_elementwise_fma(
                        (v2f){hv.z, hv.w}, (v2f){w4[gq].z, w4[gq].w},
                        acc[pp][kk][gq]);
                }
            }
        }
    }

#pragma unroll
    for (int pp = 0; pp < 2; ++pp) {
        float s[4];
#pragma unroll
        for (int gq = 0; gq < 4; ++gq) {
            s[gq] = 0.0f;
#pragma unroll
            for (int kk = 0; kk < 4; ++kk) {
                const float v = acc[pp][kk][gq].x + acc[pp][kk][gq].y;
                s[gq] += fmaxf(v, 0.0f);
            }
        }
#pragma unroll
        for (int off = 16; off <= 32; off <<= 1)
#pragma unroll
            for (int gq = 0; gq < 4; ++gq)
                s[gq] += __shfl_xor(s[gq], off, 64);

        out[(p0 + pp) * H_DIM + kq * 16 + gp] = s[kq] * (1.0f / 16.0f);
    }
}

extern "C" void kernel_launch(void* const* d_in, const int* in_sizes, int n_in,
                              void* d_out, int out_size, void* d_ws, size_t ws_size,
                              hipStream_t stream) {
    (void)in_sizes; (void)n_in; (void)out_size; (void)ws_size;
    const float* x  = (const float*)d_in[0];
    const float* W1 = (const float*)d_in[1];
    const float* b1 = (const float*)d_in[2];
    const float* W2 = (const float*)d_in[3];
    const float* b2 = (const float*)d_in[4];
    float* out = (float*)d_out;

    float* pl  = (float*)d_ws;                                      // 5*N floats
    int*   knn = (int*)((char*)d_ws + 5 * N_PTS * sizeof(float));   // N*K ints

    const float4* x4 = (const float4*)x;

    plane_kernel<<<N_PTS / 256, 256, 0, stream>>>(x4, pl);
    knn_kernel  <<<N_PTS / 8,   256, 0, stream>>>(x4, pl, knn);
    mlp_kernel  <<<N_PTS / 8,   256, 0, stream>>>(
        x4, knn, (const float4*)W2, W1, b1, b2, out);
}